// Round 6
// baseline (158.584 us; speedup 1.0000x reference)
//
#include <hip/hip_runtime.h>
#include <math.h>

#define IMG_H  384
#define IMG_W  384
#define IMG_HW (IMG_H * IMG_W)
#define NB     4
#define NC     3
#define NK     48
#define NH     24          /* taps per lane-half */

struct PosAdd { float v[NK]; };

__global__ __launch_bounds__(256, 8) void LLA_41412074668179_kernel(
    const float* __restrict__ imgs, float* __restrict__ out, PosAdd pa)
{
    const int tid  = threadIdx.x;
    const int lane = tid & 63;
    const int t    = lane >> 5;              // 0 -> dil{1,2,4}=k0..23, 1 -> dil{8,12,24}=k24..47
    // XCD-chunked swizzle: 4608 blocks = 8 XCDs x 576 contiguous chunks
    const int lb = (blockIdx.x & 7) * 576 + (blockIdx.x >> 3);
    // half-wave (32 lanes) covers 32 consecutive pixels; both halves same pixels
    const int px   = lb * 128 + (tid >> 6) * 32 + (lane & 31);
    const int w  = px % IMG_W;
    const int hb = px / IMG_W;
    const int h  = hb % IMG_H;
    const int b  = hb / IMG_H;

    const int dils[3] = { t ? 8 : 1, t ? 12 : 2, t ? 24 : 4 };

    const int r0 = h * IMG_W;
    int rm[3], rp[3], cm[3], cp[3];
#pragma unroll
    for (int di = 0; di < 3; ++di) {
        const int d = dils[di];
        rm[di] = max(h - d, 0) * IMG_W;
        rp[di] = min(h + d, IMG_H - 1) * IMG_W;
        cm[di] = max(w - d, 0);
        cp[di] = min(w + d, IMG_W - 1);
    }

    float acc[NH];
#pragma unroll
    for (int j = 0; j < NH; ++j) acc[j] = 0.0f;

#pragma unroll
    for (int c = 0; c < NC; ++c) {
        const float* __restrict__ pc = imgs + ((size_t)b * NC + c) * IMG_HW;
        const float x = pc[r0 + w];

        // ---- pass 1: stats only; taps are NOT kept live (VGPR diet -> 8 waves/SIMD)
        float s0 = 0.0f, s1 = 0.0f, q0 = 0.0f, q1 = 0.0f;
#pragma unroll
        for (int di = 0; di < 3; ++di) {
            const float t0 = pc[rm[di] + cm[di]];
            const float t1 = pc[rm[di] + w];
            const float t2 = pc[rm[di] + cp[di]];
            const float t3 = pc[r0     + cm[di]];
            const float t4 = pc[r0     + cp[di]];
            const float t5 = pc[rp[di] + cm[di]];
            const float t6 = pc[rp[di] + w];
            const float t7 = pc[rp[di] + cp[di]];
            s0 += (t0 + t1) + (t2 + t3);
            s1 += (t4 + t5) + (t6 + t7);
            q0 = fmaf(t0, t0, fmaf(t1, t1, fmaf(t2, t2, fmaf(t3, t3, q0))));
            q1 = fmaf(t4, t4, fmaf(t5, t5, fmaf(t6, t6, fmaf(t7, t7, q1))));
        }
        float s  = s0 + s1;
        float ss = q0 + q1;
        s  += __shfl_xor(s, 32);
        ss += __shfl_xor(ss, 32);

        const float mean = s * (1.0f / 48.0f);
        const float var  = fmaxf((ss - s * mean) * (1.0f / 47.0f), 0.0f);
        const float scl  = __builtin_amdgcn_rcpf(
                               fmaf(__builtin_amdgcn_sqrtf(var), 0.3f, 3.0e-9f));
        const float xs = x * scl;

        // ---- pass 2: reload taps (L1/L2-hot, ~9KB block footprint) and accumulate
#pragma unroll
        for (int di = 0; di < 3; ++di) {
            const float t0 = pc[rm[di] + cm[di]];
            const float t1 = pc[rm[di] + w];
            const float t2 = pc[rm[di] + cp[di]];
            const float t3 = pc[r0     + cm[di]];
            const float t4 = pc[r0     + cp[di]];
            const float t5 = pc[rp[di] + cm[di]];
            const float t6 = pc[rp[di] + w];
            const float t7 = pc[rp[di] + cp[di]];
            const float d0 = fmaf(t0, scl, -xs);
            const float d1 = fmaf(t1, scl, -xs);
            const float d2 = fmaf(t2, scl, -xs);
            const float d3 = fmaf(t3, scl, -xs);
            const float d4 = fmaf(t4, scl, -xs);
            const float d5 = fmaf(t5, scl, -xs);
            const float d6 = fmaf(t6, scl, -xs);
            const float d7 = fmaf(t7, scl, -xs);
            acc[di*8+0] = fmaf(d0, d0, acc[di*8+0]);
            acc[di*8+1] = fmaf(d1, d1, acc[di*8+1]);
            acc[di*8+2] = fmaf(d2, d2, acc[di*8+2]);
            acc[di*8+3] = fmaf(d3, d3, acc[di*8+3]);
            acc[di*8+4] = fmaf(d4, d4, acc[di*8+4]);
            acc[di*8+5] = fmaf(d5, d5, acc[di*8+5]);
            acc[di*8+6] = fmaf(d6, d6, acc[di*8+6]);
            acc[di*8+7] = fmaf(d7, d7, acc[di*8+7]);
        }
    }

    // softmax over all 48: max(aff) == min(acc); cross-half via shfl
    float m0 = fminf(acc[0], acc[1]), m1 = fminf(acc[2], acc[3]);
    float m2 = fminf(acc[4], acc[5]), m3 = fminf(acc[6], acc[7]);
#pragma unroll
    for (int j = 8; j < NH; j += 8) {
        m0 = fminf(m0, fminf(acc[j+0], acc[j+1]));
        m1 = fminf(m1, fminf(acc[j+2], acc[j+3]));
        m2 = fminf(m2, fminf(acc[j+4], acc[j+5]));
        m3 = fminf(m3, fminf(acc[j+6], acc[j+7]));
    }
    float mn = fminf(fminf(m0, m1), fminf(m2, m3));
    mn = fminf(mn, __shfl_xor(mn, 32));

    const float SC   = (1.0f / 3.0f) * 1.44269504f;   // /3 then ln->log2
    const float mnSC = mn * SC;
    float e0 = 0.0f, e1 = 0.0f, e2 = 0.0f, e3 = 0.0f;
#pragma unroll
    for (int j = 0; j < NH; j += 4) {
        acc[j+0] = __builtin_amdgcn_exp2f(fmaf(acc[j+0], -SC, mnSC));
        acc[j+1] = __builtin_amdgcn_exp2f(fmaf(acc[j+1], -SC, mnSC));
        acc[j+2] = __builtin_amdgcn_exp2f(fmaf(acc[j+2], -SC, mnSC));
        acc[j+3] = __builtin_amdgcn_exp2f(fmaf(acc[j+3], -SC, mnSC));
        e0 += acc[j+0]; e1 += acc[j+1]; e2 += acc[j+2]; e3 += acc[j+3];
    }
    float se = (e0 + e1) + (e2 + e3);
    se += __shfl_xor(se, 32);
    const float inv = __builtin_amdgcn_rcpf(se);

    float* __restrict__ op = out + ((size_t)(b * NK + t * NH)) * IMG_HW + r0 + w;
#pragma unroll
    for (int j = 0; j < NH; ++j) {
        const float pav = t ? pa.v[NH + j] : pa.v[j];
        __builtin_nontemporal_store(fmaf(acc[j], inv, pav),
                                    op + (size_t)j * IMG_HW);
    }
}

static void compute_pos_add(float* out48)
{
    const int DIL[6] = {1, 2, 4, 8, 12, 24};
    const double SQ2 = 1.4142135623730951;
    const double diag[8] = {SQ2, 1.0, SQ2, 1.0, 1.0, SQ2, 1.0, SQ2};

    double pos[NK];
    for (int di = 0; di < 6; ++di)
        for (int tp = 0; tp < 8; ++tp)
            pos[di * 8 + tp] = (double)((float)(diag[tp] * DIL[di]));  // match fp32 concat

    double s = 0.0;
    for (int k = 0; k < NK; ++k) s += pos[k];
    const double m = s / NK;
    double v = 0.0;
    for (int k = 0; k < NK; ++k) { const double d = pos[k] - m; v += d * d; }
    v /= (NK - 1);
    const double stdv = sqrt(v);

    double aff[NK];
    double mx = -1e300;
    for (int k = 0; k < NK; ++k) {
        const double q = pos[k] / ((stdv + 1e-8) * 0.3);
        aff[k] = -(q * q);
        if (aff[k] > mx) mx = aff[k];
    }
    double se = 0.0;
    for (int k = 0; k < NK; ++k) { aff[k] = exp(aff[k] - mx); se += aff[k]; }
    for (int k = 0; k < NK; ++k) out48[k] = (float)(0.01 * aff[k] / se);
}

extern "C" void kernel_launch(void* const* d_in, const int* in_sizes, int n_in,
                              void* d_out, int out_size, void* d_ws, size_t ws_size,
                              hipStream_t stream)
{
    const float* imgs = (const float*)d_in[0];
    float* out = (float*)d_out;

    PosAdd pa;
    compute_pos_add(pa.v);

    // 2 thread-slots per pixel (k-split across lane halves)
    const int blocks = (NB * IMG_H * IMG_W * 2) / 256;   // 4608
    LLA_41412074668179_kernel<<<blocks, 256, 0, stream>>>(imgs, out, pa);
}

// Round 7
// 38.691 us; speedup vs baseline: 4.0987x; 4.0987x over previous
//
#include <hip/hip_runtime.h>
#include <math.h>

#define IMG_H  384
#define IMG_W  384
#define IMG_HW (IMG_H * IMG_W)
#define NB     4
#define NC     3
#define NK     48
#define BW     192          /* pixels (= threads) per block: half a row */
#define SCOLS  240          /* staged cols per row segment: BW + 2*24 */
#define NROW   13           /* tap rows: 0,+-1,+-2,+-4,+-8,+-12,+-24 */
#define NSEG   (NC * NROW)  /* 39 staged segments */
#define SEGF4  (SCOLS / 4)  /* 60 */
#define TOTF4  (NSEG * SEGF4) /* 2340 */

typedef float f4 __attribute__((ext_vector_type(4)));

struct PosAdd { float v[NK]; };

__global__ __launch_bounds__(BW, 3) void LLA_41412074668179_kernel(
    const float* __restrict__ imgs, float* __restrict__ out, PosAdd pa)
{
    const int tid = threadIdx.x;

    // XCD-chunked swizzle: 3072 blocks = 8 XCDs x 384 contiguous (192 rows/XCD)
    const int lb = (blockIdx.x & 7) * 384 + (blockIdx.x >> 3);
    const int R  = lb >> 1;               // global row id (b*384 + h)
    const int c0 = (lb & 1) * BW;         // column origin of this block
    const int b  = R / IMG_H;
    const int h  = R - b * IMG_H;

    // LDS: 39 segments x 240 floats (37.4 KB). Segment s = c*13 + ri holds
    // channel c, tap-row ri, global cols [c0-24, c0+216) with col-clamp baked in.
    __shared__ __align__(16) float slds[NSEG * SCOLS];
    __shared__ int gbase[NSEG];

    if (tid < NSEG) {
        const int c  = (tid >= 26) ? 2 : (tid >= 13 ? 1 : 0);
        const int ri = tid - c * 13;
        const int off =
            ri == 0 ? -24 : ri == 1 ? -12 : ri == 2 ? -8 : ri == 3 ? -4 :
            ri == 4 ?  -2 : ri == 5 ?  -1 : ri == 6 ?  0 : ri == 7 ?  1 :
            ri == 8 ?   2 : ri == 9 ?   4 : ri == 10 ? 8 : ri == 11 ? 12 : 24;
        const int hr = min(max(h + off, 0), IMG_H - 1);
        gbase[tid] = (b * NC + c) * IMG_HW + hr * IMG_W;
    }
    __syncthreads();

    // cooperative staging: 2340 aligned dwordx4, col-clamped branchlessly.
    // g multiple of 4 => left-clamp region is all x[0], right-clamp all x[383].
#pragma unroll
    for (int k = 0; k < 13; ++k) {
        const int lin = k * BW + tid;
        if (lin < TOTF4) {
            const int s  = lin / SEGF4;
            const int q  = lin - s * SEGF4;
            const int g  = c0 - 24 + 4 * q;
            const int gc = min(max(g, 0), IMG_W - 4);
            const f4 L0 = *(const f4*)(imgs + gbase[s] + gc);
            f4 L = (g < 0) ? (f4){L0.x, L0.x, L0.x, L0.x}
                           : ((g > IMG_W - 4) ? (f4){L0.w, L0.w, L0.w, L0.w} : L0);
            *(f4*)(slds + s * SCOLS + 4 * q) = L;
        }
    }
    __syncthreads();

    // ---- compute: 1 thread = 1 pixel, all 48 taps from LDS (2-way = free banks)
    const int wl  = tid;
    const int ctr = wl + 24;
    const int DIL[6] = {1, 2, 4, 8, 12, 24};

    float acc[NK];
#pragma unroll
    for (int j = 0; j < NK; ++j) acc[j] = 0.0f;

#pragma unroll
    for (int c = 0; c < NC; ++c) {
        const float* __restrict__ Lc = slds + c * (NROW * SCOLS);
        const float x = Lc[6 * SCOLS + ctr];

        float nbv[NK];
#pragma unroll
        for (int di = 0; di < 6; ++di) {
            const int d = DIL[di];
            const float* __restrict__ rM = Lc + (5 - di) * SCOLS;  // row -d
            const float* __restrict__ rC = Lc + 6 * SCOLS;         // row 0
            const float* __restrict__ rP = Lc + (7 + di) * SCOLS;  // row +d
            nbv[di*8+0] = rM[ctr - d];
            nbv[di*8+1] = rM[ctr];
            nbv[di*8+2] = rM[ctr + d];
            nbv[di*8+3] = rC[ctr - d];
            nbv[di*8+4] = rC[ctr + d];
            nbv[di*8+5] = rP[ctr - d];
            nbv[di*8+6] = rP[ctr];
            nbv[di*8+7] = rP[ctr + d];
        }

        float s0 = 0, s1 = 0, s2 = 0, s3 = 0;
        float q0 = 0, q1 = 0, q2 = 0, q3 = 0;
#pragma unroll
        for (int j = 0; j < NK; j += 4) {
            s0 += nbv[j];   s1 += nbv[j+1];
            s2 += nbv[j+2]; s3 += nbv[j+3];
            q0 = fmaf(nbv[j],   nbv[j],   q0);
            q1 = fmaf(nbv[j+1], nbv[j+1], q1);
            q2 = fmaf(nbv[j+2], nbv[j+2], q2);
            q3 = fmaf(nbv[j+3], nbv[j+3], q3);
        }
        const float s  = (s0 + s1) + (s2 + s3);
        const float ss = (q0 + q1) + (q2 + q3);

        const float mean = s * (1.0f / 48.0f);
        const float var  = fmaxf((ss - s * mean) * (1.0f / 47.0f), 0.0f);
        const float scl  = __builtin_amdgcn_rcpf(
                               fmaf(__builtin_amdgcn_sqrtf(var), 0.3f, 3.0e-9f));
        const float xs = x * scl;

#pragma unroll
        for (int j = 0; j < NK; ++j) {
            const float dd = fmaf(nbv[j], scl, -xs);
            acc[j] = fmaf(dd, dd, acc[j]);
        }
    }

    // softmax over 48: max(aff) == min(acc)
    float m0 = fminf(acc[0], acc[1]), m1 = fminf(acc[2], acc[3]);
    float m2 = fminf(acc[4], acc[5]), m3 = fminf(acc[6], acc[7]);
#pragma unroll
    for (int j = 8; j < NK; j += 8) {
        m0 = fminf(m0, fminf(acc[j+0], acc[j+1]));
        m1 = fminf(m1, fminf(acc[j+2], acc[j+3]));
        m2 = fminf(m2, fminf(acc[j+4], acc[j+5]));
        m3 = fminf(m3, fminf(acc[j+6], acc[j+7]));
    }
    const float mn = fminf(fminf(m0, m1), fminf(m2, m3));

    const float SC   = (1.0f / 3.0f) * 1.44269504f;   // /3 then ln->log2
    const float mnSC = mn * SC;
    float e0 = 0, e1 = 0, e2 = 0, e3 = 0;
#pragma unroll
    for (int j = 0; j < NK; j += 4) {
        acc[j+0] = __builtin_amdgcn_exp2f(fmaf(acc[j+0], -SC, mnSC));
        acc[j+1] = __builtin_amdgcn_exp2f(fmaf(acc[j+1], -SC, mnSC));
        acc[j+2] = __builtin_amdgcn_exp2f(fmaf(acc[j+2], -SC, mnSC));
        acc[j+3] = __builtin_amdgcn_exp2f(fmaf(acc[j+3], -SC, mnSC));
        e0 += acc[j+0]; e1 += acc[j+1]; e2 += acc[j+2]; e3 += acc[j+3];
    }
    const float se  = (e0 + e1) + (e2 + e3);
    const float inv = __builtin_amdgcn_rcpf(se);

    float* __restrict__ op = out + ((size_t)b * NK) * IMG_HW + h * IMG_W + c0 + wl;
#pragma unroll
    for (int j = 0; j < NK; ++j) {
        __builtin_nontemporal_store(fmaf(acc[j], inv, pa.v[j]),
                                    op + (size_t)j * IMG_HW);
    }
}

static void compute_pos_add(float* out48)
{
    const int DIL[6] = {1, 2, 4, 8, 12, 24};
    const double SQ2 = 1.4142135623730951;
    const double diag[8] = {SQ2, 1.0, SQ2, 1.0, 1.0, SQ2, 1.0, SQ2};

    double pos[NK];
    for (int di = 0; di < 6; ++di)
        for (int tp = 0; tp < 8; ++tp)
            pos[di * 8 + tp] = (double)((float)(diag[tp] * DIL[di]));  // match fp32 concat

    double s = 0.0;
    for (int k = 0; k < NK; ++k) s += pos[k];
    const double m = s / NK;
    double v = 0.0;
    for (int k = 0; k < NK; ++k) { const double d = pos[k] - m; v += d * d; }
    v /= (NK - 1);
    const double stdv = sqrt(v);

    double aff[NK];
    double mx = -1e300;
    for (int k = 0; k < NK; ++k) {
        const double q = pos[k] / ((stdv + 1e-8) * 0.3);
        aff[k] = -(q * q);
        if (aff[k] > mx) mx = aff[k];
    }
    double se = 0.0;
    for (int k = 0; k < NK; ++k) { aff[k] = exp(aff[k] - mx); se += aff[k]; }
    for (int k = 0; k < NK; ++k) out48[k] = (float)(0.01 * aff[k] / se);
}

extern "C" void kernel_launch(void* const* d_in, const int* in_sizes, int n_in,
                              void* d_out, int out_size, void* d_ws, size_t ws_size,
                              hipStream_t stream)
{
    const float* imgs = (const float*)d_in[0];
    float* out = (float*)d_out;

    PosAdd pa;
    compute_pos_add(pa.v);

    // 1 thread per pixel, 192-px (half-row) blocks, all 48 taps from LDS
    const int blocks = NB * IMG_H * 2;    // 3072
    LLA_41412074668179_kernel<<<blocks, BW, 0, stream>>>(imgs, out, pa);
}